// Round 1
// baseline (586.270 us; speedup 1.0000x reference)
//
#include <hip/hip_runtime.h>
#include <hip/hip_bf16.h>
#include <math.h>

#define BB 64
#define TT 512
#define FF 1024
#define KK 64

// ---------------- Emission GEMM: em[row][k] = dot(X[row,:], W[k,:]) + b[k] ----------------
// row = b*T+t (32768 rows), K tags = 64 cols, F = 1024 reduce.
#define BM 64
#define BF 64
#define LDA 68  // padded LDS stride (floats): 68*4=272 bytes, 16B-aligned rows, breaks bank conflicts

__global__ __launch_bounds__(256)
void emission_kernel(const float* __restrict__ X, const float* __restrict__ W,
                     const float* __restrict__ bias, float* __restrict__ em)
{
    __shared__ float As[BF][LDA];   // As[f][m]  (transposed)
    __shared__ float Bs[BF][LDA];   // Bs[f][k]  (transposed)
    const int tid = threadIdx.x;
    const int row0 = blockIdx.x * BM;
    const int tm = tid & 15;        // micro-tile row group
    const int tn = tid >> 4;        // micro-tile col group
    const int lq = tid & 15;        // float4 index along f
    const int lr = tid >> 4;        // row within 16-row pass

    float acc[4][4];
#pragma unroll
    for (int i = 0; i < 4; ++i)
#pragma unroll
        for (int j = 0; j < 4; ++j) acc[i][j] = 0.f;

    for (int f0 = 0; f0 < FF; f0 += BF) {
#pragma unroll
        for (int p = 0; p < 4; ++p) {
            const int r = p * 16 + lr;
            float4 a = *(const float4*)(X + (size_t)(row0 + r) * FF + f0 + lq * 4);
            As[lq * 4 + 0][r] = a.x;
            As[lq * 4 + 1][r] = a.y;
            As[lq * 4 + 2][r] = a.z;
            As[lq * 4 + 3][r] = a.w;
            float4 w = *(const float4*)(W + (size_t)r * FF + f0 + lq * 4);
            Bs[lq * 4 + 0][r] = w.x;
            Bs[lq * 4 + 1][r] = w.y;
            Bs[lq * 4 + 2][r] = w.z;
            Bs[lq * 4 + 3][r] = w.w;
        }
        __syncthreads();
#pragma unroll
        for (int f = 0; f < BF; ++f) {
            float4 a = *(const float4*)&As[f][tm * 4];
            float4 b = *(const float4*)&Bs[f][tn * 4];
            acc[0][0] += a.x * b.x; acc[0][1] += a.x * b.y; acc[0][2] += a.x * b.z; acc[0][3] += a.x * b.w;
            acc[1][0] += a.y * b.x; acc[1][1] += a.y * b.y; acc[1][2] += a.y * b.z; acc[1][3] += a.y * b.w;
            acc[2][0] += a.z * b.x; acc[2][1] += a.z * b.y; acc[2][2] += a.z * b.z; acc[2][3] += a.z * b.w;
            acc[3][0] += a.w * b.x; acc[3][1] += a.w * b.y; acc[3][2] += a.w * b.z; acc[3][3] += a.w * b.w;
        }
        __syncthreads();
    }

    const float4 b4 = *(const float4*)(bias + tn * 4);
#pragma unroll
    for (int i = 0; i < 4; ++i) {
        float4 o;
        o.x = acc[i][0] + b4.x;
        o.y = acc[i][1] + b4.y;
        o.z = acc[i][2] + b4.z;
        o.w = acc[i][3] + b4.w;
        *(float4*)(em + (size_t)(row0 + tm * 4 + i) * KK + tn * 4) = o;
    }
}

// ---------------- Viterbi decode: one wave per sequence, lane = next-tag j ----------------
__global__ __launch_bounds__(64)
void viterbi_kernel(const float* __restrict__ em, const void* __restrict__ maskp,
                    const float* __restrict__ startT, const float* __restrict__ endT,
                    const float* __restrict__ trans, float* __restrict__ pred)
{
    const int b = blockIdx.x;
    const int j = threadIdx.x;
    __shared__ unsigned char hist[TT][KK];  // 32 KB; hist[t][j] = best prev tag (t >= 1)

    // Preload transition column j into registers: tc[i] = trans[i][j]
    float tc[KK];
#pragma unroll
    for (int i = 0; i < KK; ++i) tc[i] = trans[i * KK + j];

    // Mask layout detection: lengths >= 256, so mask[0][1] is true.
    // uint8 layout -> byte 1 == 1; int32 little-endian -> byte 1 == 0.
    const unsigned char* m8 = (const unsigned char*)maskp;
    const int* m32 = (const int*)maskp;
    const bool mask_is_u8 = (m8[1] != 0);

    const float* emb = em + (size_t)b * TT * KK;
    float score = startT[j] + emb[j];   // t = 0

    for (int t = 1; t < TT; ++t) {
        const bool mt = mask_is_u8 ? (m8[b * TT + t] != 0) : (m32[b * TT + t] != 0);
        if (mt) {  // uniform branch across the wave
            const float e = emb[(size_t)t * KK + j];
            float m = -__builtin_inff();
            int idx = 0;
#pragma unroll
            for (int i = 0; i < KK; ++i) {
                const float si = __uint_as_float(
                    __builtin_amdgcn_readlane(__float_as_uint(score), i));
                const float v = (si + tc[i]) + e;   // match reference association order
                if (v > m) { m = v; idx = i; }      // strict >: first-index argmax
            }
            score = m;
            hist[t][j] = (unsigned char)idx;
        } else {
            hist[t][j] = (unsigned char)j;          // identity (carry tag forward)
        }
    }

    score += endT[j];

    // argmax over lanes (first max), computed uniformly in all lanes
    float bm = -__builtin_inff();
    int bt = 0;
#pragma unroll
    for (int i = 0; i < KK; ++i) {
        const float si = __uint_as_float(
            __builtin_amdgcn_readlane(__float_as_uint(score), i));
        if (si > bm) { bm = si; bt = i; }
    }

    __syncthreads();  // make all hist writes visible before backtrack

    if (j == 0) {
        int tag = bt;
        float* pb = pred + (size_t)b * TT;
        pb[TT - 1] = (float)tag;
        for (int t = TT - 1; t >= 1; --t) {
            tag = hist[t][tag];
            pb[t - 1] = (float)tag;
        }
    }
}

extern "C" void kernel_launch(void* const* d_in, const int* in_sizes, int n_in,
                              void* d_out, int out_size, void* d_ws, size_t ws_size,
                              hipStream_t stream) {
    const float* X      = (const float*)d_in[0];   // text_vec (B,T,F) f32
    const void*  mask   = d_in[1];                 // mask (B,T) bool/int (runtime-detected)
    const float* W      = (const float*)d_in[2];   // (K,F) f32
    const float* bias   = (const float*)d_in[3];   // (K,) f32
    const float* startT = (const float*)d_in[4];   // (K,) f32
    const float* endT   = (const float*)d_in[5];   // (K,) f32
    const float* trans  = (const float*)d_in[6];   // (K,K) f32

    float* em   = (float*)d_out;                        // (B,1,T,K) f32
    float* pred = (float*)d_out + (size_t)BB * TT * KK; // (B,1,T) tags as f32

    emission_kernel<<<(BB * TT) / BM, 256, 0, stream>>>(X, W, bias, em);
    viterbi_kernel<<<BB, 64, 0, stream>>>(em, mask, startT, endT, trans, pred);
}